// Round 11
// baseline (144.309 us; speedup 1.0000x reference)
//
#include <hip/hip_runtime.h>

// TriangleMultiplicativeModule: B=1, L=512, D=H=64, fp32 in/out.
// Pipeline: K0 weight prep -> K1 LN+5 proj (MFMA bf16, 2-pass epilogue-early,
// LDS-bounced coalesced stores) -> K2 einsum (64x batched 512^3 GEMM, MFMA
// bf16, 256^2 tiles) -> K3 out-LN + out proj + gate (fp32 VALU).
//
// Global bf16 operand layouts are k-contiguous [h][col][k] with a baked XOR
// swizzle on 16B chunks within each 8-chunk (64-elem) window:
//   chunk position q of row holds k-chunk (q ^ (row&7))
// so LDS staging in K2 is a pure linear copy and ds_read_b128 fragment reads
// are bank-conflict-free.
// ogate layout: [row][col][d] (k3 reads contiguous; k1 stores via LDS bounce).

typedef __attribute__((ext_vector_type(4))) float f32x4;
typedef __attribute__((ext_vector_type(8))) __bf16 bf16x8;

__device__ __forceinline__ unsigned short f2bf(float f) {
  unsigned u = __float_as_uint(f);
  u += 0x7FFFu + ((u >> 16) & 1u);   // RNE
  return (unsigned short)(u >> 16);
}
__device__ __forceinline__ float bf2f(unsigned short h) {
  return __uint_as_float(((unsigned)h) << 16);
}
// packed pair-convert: compiler lowers __bf16 casts to v_cvt_pk_bf16_f32 (RNE)
__device__ __forceinline__ unsigned pk2bf(float a, float b) {
  unsigned short ua = __builtin_bit_cast(unsigned short, (__bf16)a);
  unsigned short ub = __builtin_bit_cast(unsigned short, (__bf16)b);
  return (unsigned)ua | ((unsigned)ub << 16);
}
__device__ __forceinline__ float sigm(float x) { return 1.0f / (1.0f + __expf(-x)); }

// ---------------- K0: weight prep ----------------
// wt[320][64] bf16: rows [left|right|lgate|rgate|ogate]; row n holds W[:,ch]
// k-contiguous, 16B chunks swizzled: pos q holds chunk q^(n&7).
__global__ __launch_bounds__(256) void k0_prep(
    const float* __restrict__ lw, const float* __restrict__ rw,
    const float* __restrict__ lgw, const float* __restrict__ rgw,
    const float* __restrict__ ogw, unsigned short* __restrict__ wt) {
  const int t = threadIdx.x;
  #pragma unroll
  for (int e = 0; e < 80; ++e) {
    int idx = e * 256 + t;  // [0, 20480)
    int n = idx >> 6, k = idx & 63;
    const float* W = (n < 64) ? lw : (n < 128) ? rw : (n < 192) ? lgw
                     : (n < 256) ? rgw : ogw;
    float v = W[k * 64 + (n & 63)];
    int el = n * 64 + ((((k >> 3) ^ (n & 7)) << 3) | (k & 7));
    wt[el] = f2bf(v);
  }
}

// ---------------- K1: LN + 5 projections + gates + mask ----------------
// Block: 512 threads (8 waves), 128 positions (rows r0..r0+127 at fixed col c).
// 2-pass MFMA: pass A = left/right/lgate/rgate (16 accs, epilogue folded to
// packed VGPRs immediately), pass B = ogate (4 accs, swapped operands, A-frags
// reused from registers). Peak regs ~64 VGPR + 64 AGPR -> 4 waves/SIMD.
// x loads hoisted above weight staging to hide HBM latency.
__global__ __launch_bounds__(512) void k1_proj(
    const float* __restrict__ x, const int* __restrict__ smask,
    const float* __restrict__ norm_w, const float* __restrict__ norm_b,
    const float* __restrict__ left_b, const float* __restrict__ right_b,
    const float* __restrict__ lgate_b, const float* __restrict__ rgate_b,
    const float* __restrict__ ogate_b, const unsigned short* __restrict__ wt,
    unsigned short* __restrict__ left_t, unsigned short* __restrict__ right_t,
    unsigned short* __restrict__ ogate) {
  __shared__ __align__(16) char ldsWt[40960];  // weights; reused as L/R bounce
  __shared__ __align__(16) char ldsX[16384];   // xn swizzled; reused as OG bounce
  __shared__ float sNW[64], sNB[64];
  __shared__ __align__(16) float sLB[64], sRB[64], sLGB[64], sRGB[64], sOGB[64];
  __shared__ float sMK[128];

  const int t = threadIdx.x;
  const int c = blockIdx.x & 511;
  const int r0 = (blockIdx.x >> 9) << 7;

  // x loads FIRST (latency hides under weight staging + barrier)
  const int m = t >> 2, q = t & 3;
  float v[16];
  {
    const float* xp = x + ((size_t)(r0 + m) * 512 + c) * 64 + q * 16;
    #pragma unroll
    for (int i = 0; i < 4; ++i) {
      float4 f = *(const float4*)(xp + i * 4);
      v[i*4+0] = f.x; v[i*4+1] = f.y; v[i*4+2] = f.z; v[i*4+3] = f.w;
    }
  }

  // stage weights: linear copy (already swizzled in global)
  #pragma unroll
  for (int i = 0; i < 5; ++i) {
    int u = t + i * 512;
    *(uint4*)(ldsWt + u * 16) = *(const uint4*)((const char*)wt + u * 16);
  }
  if (t < 64) {
    sNW[t] = norm_w[t]; sNB[t] = norm_b[t];
    sLB[t] = left_b[t]; sRB[t] = right_b[t];
    sLGB[t] = lgate_b[t]; sRGB[t] = rgate_b[t]; sOGB[t] = ogate_b[t];
  }
  if (t >= 64 && t < 192) sMK[t - 64] = (float)smask[r0 + (t - 64)];
  __syncthreads();

  // phase 1: LayerNorm (4 threads/position, 16 ch each; 128 positions)
  {
    float s = 0.f, ss = 0.f;
    #pragma unroll
    for (int i = 0; i < 16; ++i) { s += v[i]; ss += v[i] * v[i]; }
    s += __shfl_xor(s, 1); s += __shfl_xor(s, 2);
    ss += __shfl_xor(ss, 1); ss += __shfl_xor(ss, 2);
    const float mu = s * 0.015625f;
    const float rs = rsqrtf(ss * 0.015625f - mu * mu + 1e-5f);
    unsigned pk[8];
    #pragma unroll
    for (int i = 0; i < 8; ++i) {
      const int d0 = q * 16 + 2 * i;
      pk[i] = pk2bf((v[2*i]   - mu) * rs * sNW[d0]     + sNB[d0],
                    (v[2*i+1] - mu) * rs * sNW[d0 + 1] + sNB[d0 + 1]);
    }
    uint4 lo; lo.x = pk[0]; lo.y = pk[1]; lo.z = pk[2]; lo.w = pk[3];
    uint4 hi; hi.x = pk[4]; hi.y = pk[5]; hi.z = pk[6]; hi.w = pk[7];
    *(uint4*)(ldsX + m * 128 + (((q * 2)     ^ (m & 7)) << 4)) = lo;
    *(uint4*)(ldsX + m * 128 + (((q * 2 + 1) ^ (m & 7)) << 4)) = hi;
  }
  __syncthreads();

  // phase 2, pass A: 16 frags (left 0-3, right 4-7, lgate 8-11, rgate 12-15)
  const int w = t >> 6, l = t & 63, lr = l & 15, g = l >> 4;
  const int rowA = w * 16 + lr;
  const int soff0 = ((g ^ (lr & 7)) << 4);
  const int soff1 = (((4 + g) ^ (lr & 7)) << 4);
  const bf16x8 a0 = *(const bf16x8*)(ldsX + rowA * 128 + soff0);
  const bf16x8 a1 = *(const bf16x8*)(ldsX + rowA * 128 + soff1);
  uint2 lpk[4], rpk[4], gpk[4];
  {
    f32x4 acc[16];
    #pragma unroll
    for (int nf = 0; nf < 16; ++nf) acc[nf] = (f32x4){0.f, 0.f, 0.f, 0.f};
    #pragma unroll
    for (int nf = 0; nf < 16; ++nf) {
      bf16x8 bb = *(const bf16x8*)(ldsWt + (nf * 16 + lr) * 128 + soff0);
      acc[nf] = __builtin_amdgcn_mfma_f32_16x16x32_bf16(a0, bb, acc[nf], 0, 0, 0);
    }
    #pragma unroll
    for (int nf = 0; nf < 16; ++nf) {
      bf16x8 bb = *(const bf16x8*)(ldsWt + (nf * 16 + lr) * 128 + soff1);
      acc[nf] = __builtin_amdgcn_mfma_f32_16x16x32_bf16(a1, bb, acc[nf], 0, 0, 0);
    }
    // epilogue A folded immediately: accs -> 16 packed VGPRs
    const float mc = (float)smask[c];
    float mk[4];
    #pragma unroll
    for (int rr = 0; rr < 4; ++rr) mk[rr] = mc * sMK[w * 16 + g * 4 + rr];
    #pragma unroll
    for (int nf = 0; nf < 4; ++nf) {
      const int hh = nf * 16 + lr;
      const float lb = sLB[hh], rb = sRB[hh];
      const float lgb = sLGB[hh], rgb = sRGB[hh];
      float lo[4], ro[4];
      #pragma unroll
      for (int rr = 0; rr < 4; ++rr) {
        lo[rr] = (acc[nf][rr]     + lb) * mk[rr] * sigm(acc[8  + nf][rr] + lgb);
        ro[rr] = (acc[4 + nf][rr] + rb) * mk[rr] * sigm(acc[12 + nf][rr] + rgb);
      }
      lpk[nf].x = pk2bf(lo[0], lo[1]); lpk[nf].y = pk2bf(lo[2], lo[3]);
      rpk[nf].x = pk2bf(ro[0], ro[1]); rpk[nf].y = pk2bf(ro[2], ro[3]);
    }
  }
  // pass B: ogate (4 accs, swapped operands; A-frags from registers)
  {
    f32x4 og[4];
    #pragma unroll
    for (int nf = 0; nf < 4; ++nf) og[nf] = (f32x4){0.f, 0.f, 0.f, 0.f};
    #pragma unroll
    for (int nf = 0; nf < 4; ++nf) {
      bf16x8 bb = *(const bf16x8*)(ldsWt + ((256 + nf * 16) + lr) * 128 + soff0);
      og[nf] = __builtin_amdgcn_mfma_f32_16x16x32_bf16(bb, a0, og[nf], 0, 0, 0);
    }
    #pragma unroll
    for (int nf = 0; nf < 4; ++nf) {
      bf16x8 bb = *(const bf16x8*)(ldsWt + ((256 + nf * 16) + lr) * 128 + soff1);
      og[nf] = __builtin_amdgcn_mfma_f32_16x16x32_bf16(bb, a1, og[nf], 0, 0, 0);
    }
    #pragma unroll
    for (int nf = 0; nf < 4; ++nf) {
      const int d0 = nf * 16 + g * 4;
      const float4 ob4 = *(const float4*)&sOGB[d0];
      gpk[nf].x = pk2bf(sigm(og[nf][0] + ob4.x), sigm(og[nf][1] + ob4.y));
      gpk[nf].y = pk2bf(sigm(og[nf][2] + ob4.z), sigm(og[nf][3] + ob4.w));
    }
  }
  __syncthreads();   // all MFMA LDS reads done -> ldsWt/ldsX reusable

  // bounce writes
  char* bL = ldsWt;            // [64 ch][272B] (128 pos bf16 + 16B pad)
  char* bR = ldsWt + 17408;    // [64 ch][272B]
  {
    const int rb2 = (w * 16 + g * 4) * 2;
    #pragma unroll
    for (int nf = 0; nf < 4; ++nf) {
      const int hh = nf * 16 + lr;
      *(uint2*)(bL + hh * 272 + rb2) = lpk[nf];
      *(uint2*)(bR + hh * 272 + rb2) = rpk[nf];
    }
    const int rloc = w * 16 + lr;
    #pragma unroll
    for (int nf = 0; nf < 4; ++nf) {
      const int d0 = nf * 16 + g * 4;
      const int slot = (d0 >> 3) ^ (rloc & 7);
      *(uint2*)(ldsX + rloc * 128 + slot * 16 + (d0 & 4) * 2) = gpk[nf];
    }
  }
  __syncthreads();

  // coalesced stores: dense 16B per lane
  const int cx = c & 7;
  #pragma unroll
  for (int it = 0; it < 2; ++it) {
    const int idx = it * 512 + t;            // [0,1024)
    const int hh = idx >> 4, rel = idx & 15;
    const size_t goff = (size_t)hh * 524288 + (size_t)c * 1024 +
                        (size_t)(((r0 >> 3) + (rel & 8) + ((rel & 7) ^ cx)) << 4);
    *(uint4*)((char*)left_t  + goff) = *(const uint4*)(bL + hh * 272 + rel * 16);
    *(uint4*)((char*)right_t + goff) = *(const uint4*)(bR + hh * 272 + rel * 16);
  }
  // ogate -> [row][col][d]: per row a contiguous 128B run (8 chunks)
  #pragma unroll
  for (int it = 0; it < 2; ++it) {
    const int idx = it * 512 + t;            // [0,1024)
    const int rl = idx >> 3, ch = idx & 7;
    *(uint4*)((char*)ogate + ((size_t)(r0 + rl) * 512 + c) * 128 + ch * 16) =
        *(const uint4*)(ldsX + rl * 128 + ((ch ^ (rl & 7)) << 4));
  }
}

// ---------------- K2: einsum  o[d][i][j] = sum_k right_t[d][i][k]*left_t[d][j][k]
// 256x256 tiles: halves operand re-read traffic (268->134 MB) and doubles
// MFMA per ds_read. 512 thr = 8 waves (2x4); wave tile 128x64 (acc 8x4).
__global__ __launch_bounds__(512) void k2_einsum(
    const unsigned short* __restrict__ left_t,
    const unsigned short* __restrict__ right_t,
    unsigned short* __restrict__ o) {
  __shared__ __align__(16) char ldsA[32768];  // [256 i][64 k] bf16 swizzled
  __shared__ __align__(16) char ldsB[32768];  // [256 j][64 k]
  const int t = threadIdx.x;
  const int d = blockIdx.x >> 2;
  const int i0 = ((blockIdx.x >> 1) & 1) * 256;
  const int j0 = (blockIdx.x & 1) * 256;
  const int w = t >> 6, l = t & 63, lr = l & 15, g = l >> 4;
  const char* Rb = (const char*)right_t + (size_t)d * 524288;
  const char* Lb = (const char*)left_t  + (size_t)d * 524288;
  f32x4 acc[8][4];
  #pragma unroll
  for (int mi = 0; mi < 8; ++mi)
    #pragma unroll
    for (int nj = 0; nj < 4; ++nj) acc[mi][nj] = (f32x4){0.f, 0.f, 0.f, 0.f};
  const int wm0 = (w >> 2) * 128, wn0 = (w & 3) * 64;
  for (int kb = 0; kb < 512; kb += 64) {
    // stage: global swizzle cancels -> pure linear 128B-per-row copy
    #pragma unroll
    for (int cc = 0; cc < 4; ++cc) {
      const int p16 = (w * 4 + cc) * 64 + l;   // [0,2048)
      const int m = p16 >> 3, sl = p16 & 7;
      *(uint4*)(ldsA + p16 * 16) =
          *(const uint4*)(Rb + (size_t)(i0 + m) * 1024 + kb * 2 + sl * 16);
      *(uint4*)(ldsB + p16 * 16) =
          *(const uint4*)(Lb + (size_t)(j0 + m) * 1024 + kb * 2 + sl * 16);
    }
    __syncthreads();
    #pragma unroll
    for (int s = 0; s < 2; ++s) {
      const int soff = (((s * 4 + g) ^ (lr & 7)) << 4);
      bf16x8 af[8], bfr[4];
      #pragma unroll
      for (int mi = 0; mi < 8; ++mi)
        af[mi] = *(const bf16x8*)(ldsA + (wm0 + mi * 16 + lr) * 128 + soff);
      #pragma unroll
      for (int nj = 0; nj < 4; ++nj)
        bfr[nj] = *(const bf16x8*)(ldsB + (wn0 + nj * 16 + lr) * 128 + soff);
      #pragma unroll
      for (int mi = 0; mi < 8; ++mi)
        #pragma unroll
        for (int nj = 0; nj < 4; ++nj)
          acc[mi][nj] = __builtin_amdgcn_mfma_f32_16x16x32_bf16(
              af[mi], bfr[nj], acc[mi][nj], 0, 0, 0);
    }
    __syncthreads();
  }
  #pragma unroll
  for (int mi = 0; mi < 8; ++mi)
    #pragma unroll
    for (int nj = 0; nj < 4; ++nj)
      #pragma unroll
      for (int rr = 0; rr < 4; ++rr) {
        const int i = i0 + wm0 + mi * 16 + g * 4 + rr;
        const int j = j0 + wn0 + nj * 16 + lr;
        o[(size_t)d * 262144 + (size_t)i * 512 + j] = f2bf(acc[mi][nj][rr]);
      }
}

// ---------------- K3: out-LN + out projection + out_gate (fp32 VALU) ---------
// Validated numerics (fp32 LN, fp32 matvec, fp32 W), register-blocked.
// ogate [row][col][d]: contiguous read per position (r5-validated form).
__global__ __launch_bounds__(256) void k3_final(
    const unsigned short* __restrict__ o, const unsigned short* __restrict__ ogate,
    const float* __restrict__ onorm_w, const float* __restrict__ onorm_b,
    const float* __restrict__ out_w, const float* __restrict__ out_b,
    float* __restrict__ out) {
  __shared__ __align__(16) char ldsO[64 * 272];   // [64 d][128 p bf16 + 16B pad]
  __shared__ __align__(16) float ldsW[64 * 68];   // [64 k][64 n + 4 pad] fp32
  __shared__ float sONW[64], sONB[64], sOB[64];
  const int t = threadIdx.x;
  const int i = blockIdx.x >> 2;
  const int j0 = (blockIdx.x & 3) << 7;
  const size_t p0 = (size_t)i * 512 + j0;

  // stage o: 64 rows x 256B (16 chunks each), coalesced
  #pragma unroll
  for (int e = 0; e < 4; ++e) {
    const int u = t + e * 256;       // [0,1024)
    const int d = u >> 4, sl = u & 15;
    *(uint4*)(ldsO + d * 272 + sl * 16) =
        *(const uint4*)((const char*)o + ((size_t)d * 262144 + p0) * 2 + sl * 16);
  }
  // stage out_w fp32 (no rounding): ldsW[k*68+n]
  #pragma unroll
  for (int e = 0; e < 16; ++e) {
    const int idx = e * 256 + t;
    ldsW[(idx >> 6) * 68 + (idx & 63)] = out_w[idx];
  }
  if (t < 64) { sONW[t] = onorm_w[t]; sONB[t] = onorm_b[t]; sOB[t] = out_b[t]; }
  __syncthreads();

  const int p = t >> 1, h = t & 1;
  // LN: column read of 32 channels (bank-rotated by 272B row stride)
  float v[32];
  #pragma unroll
  for (int dl = 0; dl < 32; ++dl)
    v[dl] = bf2f(*(const unsigned short*)(ldsO + (h * 32 + dl) * 272 + p * 2));
  float s = 0.f, ss = 0.f;
  #pragma unroll
  for (int dl = 0; dl < 32; ++dl) { s += v[dl]; ss += v[dl] * v[dl]; }
  s += __shfl_xor(s, 1); ss += __shfl_xor(ss, 1);
  const float mu = s * 0.015625f;
  const float rs = rsqrtf(ss * 0.015625f - mu * mu + 1e-5f);
  float xv[32];
  #pragma unroll
  for (int dl = 0; dl < 32; ++dl) {
    const int d = h * 32 + dl;
    xv[dl] = (v[dl] - mu) * rs * sONW[d] + sONB[d];
  }

  // matvec: out[p][n0..n0+31] = sum_k xn[p][k] * W[k][n]
  const int n0 = h * 32;
  float acc[32];
  #pragma unroll
  for (int n = 0; n < 32; ++n) acc[n] = 0.f;
  #pragma unroll 4
  for (int kk = 0; kk < 32; ++kk) {
    const float a = xv[kk];
    const float* wr = ldsW + (h * 32 + kk) * 68 + n0;
    #pragma unroll
    for (int c = 0; c < 8; ++c) {
      const float4 wv = *(const float4*)(wr + c * 4);
      acc[c*4+0] += a * wv.x; acc[c*4+1] += a * wv.y;
      acc[c*4+2] += a * wv.z; acc[c*4+3] += a * wv.w;
    }
  }
  #pragma unroll 4
  for (int kk = 0; kk < 32; ++kk) {
    const float a = __shfl_xor(xv[kk], 1);
    const float* wr = ldsW + ((1 - h) * 32 + kk) * 68 + n0;
    #pragma unroll
    for (int c = 0; c < 8; ++c) {
      const float4 wv = *(const float4*)(wr + c * 4);
      acc[c*4+0] += a * wv.x; acc[c*4+1] += a * wv.y;
      acc[c*4+2] += a * wv.z; acc[c*4+3] += a * wv.w;
    }
  }

  // epilogue: +out_b, *ogate (bf16, contiguous per position), fp32 store
  const size_t pl = p0 + p;
  const unsigned short* gp = ogate + pl * 64 + n0;
  float* op = out + pl * 64 + n0;
  #pragma unroll
  for (int c = 0; c < 4; ++c) {
    const uint4 g4 = *(const uint4*)(gp + c * 8);
    const unsigned gg[4] = {g4.x, g4.y, g4.z, g4.w};
    float r[8];
    #pragma unroll
    for (int e = 0; e < 4; ++e) {
      r[2*e]   = (acc[c*8 + 2*e]   + sOB[n0 + c*8 + 2*e])   *
                 bf2f((unsigned short)(gg[e] & 0xffffu));
      r[2*e+1] = (acc[c*8 + 2*e+1] + sOB[n0 + c*8 + 2*e+1]) *
                 bf2f((unsigned short)(gg[e] >> 16));
    }
    float4 s0; s0.x = r[0]; s0.y = r[1]; s0.z = r[2]; s0.w = r[3];
    float4 s1; s1.x = r[4]; s1.y = r[5]; s1.z = r[6]; s1.w = r[7];
    *(float4*)(op + c * 8)     = s0;
    *(float4*)(op + c * 8 + 4) = s1;
  }
}

extern "C" void kernel_launch(void* const* d_in, const int* in_sizes, int n_in,
                              void* d_out, int out_size, void* d_ws, size_t ws_size,
                              hipStream_t stream) {
  const float* x       = (const float*)d_in[0];
  const int*   sm      = (const int*)d_in[1];
  const float* norm_w  = (const float*)d_in[2];
  const float* norm_b  = (const float*)d_in[3];
  const float* left_w  = (const float*)d_in[4];
  const float* left_b  = (const float*)d_in[5];
  const float* right_w = (const float*)d_in[6];
  const float* right_b = (const float*)d_in[7];
  const float* lgate_w = (const float*)d_in[8];
  const float* lgate_b = (const float*)d_in[9];
  const float* rgate_w = (const float*)d_in[10];
  const float* rgate_b = (const float*)d_in[11];
  const float* ogate_w = (const float*)d_in[12];
  const float* ogate_b = (const float*)d_in[13];
  const float* onorm_w = (const float*)d_in[14];
  const float* onorm_b = (const float*)d_in[15];
  const float* out_w   = (const float*)d_in[16];
  const float* out_b   = (const float*)d_in[17];

  char* ws = (char*)d_ws;
  unsigned short* left_t  = (unsigned short*)(ws + 0);          // 33.5 MB
  unsigned short* right_t = (unsigned short*)(ws + 33554432);   // 33.5 MB
  unsigned short* ogate   = (unsigned short*)(ws + 67108864);   // 33.5 MB
  unsigned short* obuf    = (unsigned short*)(ws + 100663296);  // 33.5 MB
  unsigned short* wt      = (unsigned short*)(ws + 134217728);  // 40 KB

  if (ws_size < (size_t)134217728 + 40960) return;  // scratch too small

  k0_prep<<<dim3(1), dim3(256), 0, stream>>>(left_w, right_w, lgate_w, rgate_w,
                                             ogate_w, wt);
  k1_proj<<<dim3(2048), dim3(512), 0, stream>>>(x, sm, norm_w, norm_b, left_b,
                                                right_b, lgate_b, rgate_b,
                                                ogate_b, wt, left_t, right_t,
                                                ogate);
  k2_einsum<<<dim3(256), dim3(512), 0, stream>>>(left_t, right_t, obuf);
  k3_final<<<dim3(2048), dim3(256), 0, stream>>>(obuf, ogate, onorm_w, onorm_b,
                                                 out_w, out_b, (float*)d_out);
}

// Round 12
// 128.960 us; speedup vs baseline: 1.1190x; 1.1190x over previous
//
#include <hip/hip_runtime.h>

// TriangleMultiplicativeModule: B=1, L=512, D=H=64, fp32 in/out.
// Pipeline: K0 weight prep -> K1 LN+5 proj (MFMA bf16, LDS-bounced coalesced
// stores) -> K2 einsum (64x batched 512^3 GEMM, MFMA bf16, 256^2 tiles,
// global_load_lds staging, XCD-grouped) -> K3 out-LN + out proj + gate.
//
// Global bf16 operand layouts are k-contiguous [h][col][k] with a baked XOR
// swizzle on 16B chunks within each 8-chunk (64-elem) window:
//   chunk position q of row holds k-chunk (q ^ (row&7))
// so LDS staging in K2 is a pure linear copy and ds_read_b128 fragment reads
// are bank-conflict-free.
// ogate layout: [row][col][d] (k3 reads contiguous; k1 stores via LDS bounce).

typedef __attribute__((ext_vector_type(4))) float f32x4;
typedef __attribute__((ext_vector_type(8))) __bf16 bf16x8;

__device__ __forceinline__ unsigned short f2bf(float f) {
  unsigned u = __float_as_uint(f);
  u += 0x7FFFu + ((u >> 16) & 1u);   // RNE
  return (unsigned short)(u >> 16);
}
__device__ __forceinline__ float bf2f(unsigned short h) {
  return __uint_as_float(((unsigned)h) << 16);
}
// packed pair-convert: compiler lowers __bf16 casts to v_cvt_pk_bf16_f32 (RNE)
__device__ __forceinline__ unsigned pk2bf(float a, float b) {
  unsigned short ua = __builtin_bit_cast(unsigned short, (__bf16)a);
  unsigned short ub = __builtin_bit_cast(unsigned short, (__bf16)b);
  return (unsigned)ua | ((unsigned)ub << 16);
}
__device__ __forceinline__ float sigm(float x) { return 1.0f / (1.0f + __expf(-x)); }

// ---------------- K0: weight prep (20 blocks) ----------------
// wt[320][64] bf16: rows [left|right|lgate|rgate|ogate]; row n holds W[:,ch]
// k-contiguous, 16B chunks swizzled: pos q holds chunk q^(n&7).
__global__ __launch_bounds__(256) void k0_prep(
    const float* __restrict__ lw, const float* __restrict__ rw,
    const float* __restrict__ lgw, const float* __restrict__ rgw,
    const float* __restrict__ ogw, unsigned short* __restrict__ wt) {
  const int t0 = blockIdx.x * 1024 + threadIdx.x;
  #pragma unroll
  for (int e = 0; e < 4; ++e) {
    int idx = t0 + e * 256;  // [0, 20480)
    int n = idx >> 6, k = idx & 63;
    const float* W = (n < 64) ? lw : (n < 128) ? rw : (n < 192) ? lgw
                     : (n < 256) ? rgw : ogw;
    float v = W[k * 64 + (n & 63)];
    int el = n * 64 + ((((k >> 3) ^ (n & 7)) << 3) | (k & 7));
    wt[el] = f2bf(v);
  }
}

// ---------------- K1: LN + 5 projections + gates + mask (r10 form) ----------
// Block: 512 threads (8 waves), 128 positions (rows r0..r0+127 at fixed col c).
// Single-pass 20-frag MFMA. Epilogue bounces results through dead LDS so all
// global stores are dense 16B-per-lane runs.
__global__ __launch_bounds__(512) void k1_proj(
    const float* __restrict__ x, const int* __restrict__ smask,
    const float* __restrict__ norm_w, const float* __restrict__ norm_b,
    const float* __restrict__ left_b, const float* __restrict__ right_b,
    const float* __restrict__ lgate_b, const float* __restrict__ rgate_b,
    const float* __restrict__ ogate_b, const unsigned short* __restrict__ wt,
    unsigned short* __restrict__ left_t, unsigned short* __restrict__ right_t,
    unsigned short* __restrict__ ogate) {
  __shared__ __align__(16) char ldsWt[40960];  // weights; reused as L/R bounce
  __shared__ __align__(16) char ldsX[16384];   // xn swizzled; reused as OG bounce
  __shared__ float sNW[64], sNB[64];
  __shared__ __align__(16) float sLB[64], sRB[64], sLGB[64], sRGB[64], sOGB[64];
  __shared__ float sMK[128];

  const int t = threadIdx.x;
  const int c = blockIdx.x & 511;
  const int r0 = (blockIdx.x >> 9) << 7;

  // stage weights: linear copy (already swizzled in global)
  #pragma unroll
  for (int i = 0; i < 5; ++i) {
    int u = t + i * 512;
    *(uint4*)(ldsWt + u * 16) = *(const uint4*)((const char*)wt + u * 16);
  }
  if (t < 64) {
    sNW[t] = norm_w[t]; sNB[t] = norm_b[t];
    sLB[t] = left_b[t]; sRB[t] = right_b[t];
    sLGB[t] = lgate_b[t]; sRGB[t] = rgate_b[t]; sOGB[t] = ogate_b[t];
  }
  if (t >= 64 && t < 192) sMK[t - 64] = (float)smask[r0 + (t - 64)];
  __syncthreads();

  // phase 1: LayerNorm (4 threads/position, 16 ch each; 128 positions)
  {
    const int m = t >> 2, q = t & 3;
    const float* xp = x + ((size_t)(r0 + m) * 512 + c) * 64 + q * 16;
    float v[16];
    #pragma unroll
    for (int i = 0; i < 4; ++i) {
      float4 f = *(const float4*)(xp + i * 4);
      v[i*4+0] = f.x; v[i*4+1] = f.y; v[i*4+2] = f.z; v[i*4+3] = f.w;
    }
    float s = 0.f, ss = 0.f;
    #pragma unroll
    for (int i = 0; i < 16; ++i) { s += v[i]; ss += v[i] * v[i]; }
    s += __shfl_xor(s, 1); s += __shfl_xor(s, 2);
    ss += __shfl_xor(ss, 1); ss += __shfl_xor(ss, 2);
    const float mu = s * 0.015625f;
    const float rs = rsqrtf(ss * 0.015625f - mu * mu + 1e-5f);
    unsigned pk[8];
    #pragma unroll
    for (int i = 0; i < 8; ++i) {
      const int d0 = q * 16 + 2 * i;
      pk[i] = pk2bf((v[2*i]   - mu) * rs * sNW[d0]     + sNB[d0],
                    (v[2*i+1] - mu) * rs * sNW[d0 + 1] + sNB[d0 + 1]);
    }
    uint4 lo; lo.x = pk[0]; lo.y = pk[1]; lo.z = pk[2]; lo.w = pk[3];
    uint4 hi; hi.x = pk[4]; hi.y = pk[5]; hi.z = pk[6]; hi.w = pk[7];
    *(uint4*)(ldsX + m * 128 + (((q * 2)     ^ (m & 7)) << 4)) = lo;
    *(uint4*)(ldsX + m * 128 + (((q * 2 + 1) ^ (m & 7)) << 4)) = hi;
  }
  __syncthreads();

  // phase 2: MFMA  out[m][n] = xn[m][k] @ W[k][n], n in [0,320)
  // nf 0..15: D[pos][n] (A=xn, B=W). nf 16..19 (ogate): SWAPPED -> D[d][pos].
  const int w = t >> 6, l = t & 63, lr = l & 15, g = l >> 4;
  f32x4 acc[20];
  #pragma unroll
  for (int nf = 0; nf < 20; ++nf) acc[nf] = (f32x4){0.f, 0.f, 0.f, 0.f};
  const int rowA = w * 16 + lr;
  #pragma unroll
  for (int s = 0; s < 2; ++s) {
    const int soff = (((s * 4 + g) ^ (lr & 7)) << 4);
    bf16x8 a = *(const bf16x8*)(ldsX + rowA * 128 + soff);
    #pragma unroll
    for (int nf = 0; nf < 16; ++nf) {
      bf16x8 bb = *(const bf16x8*)(ldsWt + (nf * 16 + lr) * 128 + soff);
      acc[nf] = __builtin_amdgcn_mfma_f32_16x16x32_bf16(a, bb, acc[nf], 0, 0, 0);
    }
    #pragma unroll
    for (int nf = 16; nf < 20; ++nf) {
      bf16x8 bb = *(const bf16x8*)(ldsWt + (nf * 16 + lr) * 128 + soff);
      acc[nf] = __builtin_amdgcn_mfma_f32_16x16x32_bf16(bb, a, acc[nf], 0, 0, 0);
    }
  }
  __syncthreads();   // all MFMA LDS reads done -> ldsWt/ldsX reusable

  // epilogue compute -> LDS bounce
  char* bL = ldsWt;            // [64 ch][272B] (128 pos bf16 + 16B pad)
  char* bR = ldsWt + 17408;    // [64 ch][272B]
  {
    const float mc = (float)smask[c];
    float mk[4];
    #pragma unroll
    for (int rr = 0; rr < 4; ++rr) mk[rr] = mc * sMK[w * 16 + g * 4 + rr];
    const int rb2 = (w * 16 + g * 4) * 2;
    #pragma unroll
    for (int nf = 0; nf < 4; ++nf) {
      const int hh = nf * 16 + lr;
      const float lb = sLB[hh], rb = sRB[hh];
      const float lgb = sLGB[hh], rgb = sRGB[hh];
      float lo[4], ro[4];
      #pragma unroll
      for (int rr = 0; rr < 4; ++rr) {
        lo[rr] = (acc[nf][rr]     + lb) * mk[rr] * sigm(acc[8  + nf][rr] + lgb);
        ro[rr] = (acc[4 + nf][rr] + rb) * mk[rr] * sigm(acc[12 + nf][rr] + rgb);
      }
      uint2 lv; lv.x = pk2bf(lo[0], lo[1]); lv.y = pk2bf(lo[2], lo[3]);
      uint2 rv; rv.x = pk2bf(ro[0], ro[1]); rv.y = pk2bf(ro[2], ro[3]);
      *(uint2*)(bL + hh * 272 + rb2) = lv;
      *(uint2*)(bR + hh * 272 + rb2) = rv;
    }
    // ogate bounce: [128 r][64 d] in ldsX, 16B chunks XOR-swizzled by (r&7)
    const int rloc = w * 16 + lr;
    #pragma unroll
    for (int nf = 0; nf < 4; ++nf) {
      const int d0 = nf * 16 + g * 4;
      const float4 ob4 = *(const float4*)&sOGB[d0];
      const float g0 = sigm(acc[16 + nf][0] + ob4.x);
      const float g1 = sigm(acc[16 + nf][1] + ob4.y);
      const float g2 = sigm(acc[16 + nf][2] + ob4.z);
      const float g3 = sigm(acc[16 + nf][3] + ob4.w);
      uint2 gv; gv.x = pk2bf(g0, g1); gv.y = pk2bf(g2, g3);
      const int slot = (d0 >> 3) ^ (rloc & 7);
      *(uint2*)(ldsX + rloc * 128 + slot * 16 + (d0 & 4) * 2) = gv;
    }
  }
  __syncthreads();

  // coalesced stores: dense 16B per lane
  const int cx = c & 7;
  #pragma unroll
  for (int it = 0; it < 2; ++it) {
    const int idx = it * 512 + t;            // [0,1024)
    const int hh = idx >> 4, rel = idx & 15;
    const size_t goff = (size_t)hh * 524288 + (size_t)c * 1024 +
                        (size_t)(((r0 >> 3) + (rel & 8) + ((rel & 7) ^ cx)) << 4);
    *(uint4*)((char*)left_t  + goff) = *(const uint4*)(bL + hh * 272 + rel * 16);
    *(uint4*)((char*)right_t + goff) = *(const uint4*)(bR + hh * 272 + rel * 16);
  }
  // ogate -> [row][col][d]: per row a contiguous 128B run (8 chunks)
  #pragma unroll
  for (int it = 0; it < 2; ++it) {
    const int idx = it * 512 + t;            // [0,1024)
    const int rl = idx >> 3, ch = idx & 7;
    *(uint4*)((char*)ogate + ((size_t)(r0 + rl) * 512 + c) * 128 + ch * 16) =
        *(const uint4*)(ldsX + rl * 128 + ((ch ^ (rl & 7)) << 4));
  }
}

// ---------------- K2: einsum  o[d][i][j] = sum_k right_t[d][i][k]*left_t[d][j][k]
// 256x256 tiles. global_load_lds staging (linear dest = wave base + lane*16).
// XCD grouping: same-d quadrants dispatch to one XCD (share operand panels in
// its L2). Epilogue: bounce 128-row halves through dead LDS -> 16B stores in
// 512B segments instead of 128 scalar 2B scatters.
__global__ __launch_bounds__(512) void k2_einsum(
    const unsigned short* __restrict__ left_t,
    const unsigned short* __restrict__ right_t,
    unsigned short* __restrict__ o) {
  __shared__ __align__(16) char lds[69632];   // A[0:32K] B[32K:64K]; bounce [128][544]
  char* ldsA = lds;
  char* ldsB = lds + 32768;
  const int t = threadIdx.x;
  const int bid = (int)blockIdx.x;
  const int id = ((bid & 7) << 5) | (bid >> 3);  // round-robin slot -> XCD group
  const int d = id >> 2;
  const int i0 = ((id >> 1) & 1) * 256;
  const int j0 = (id & 1) * 256;
  const int w = t >> 6, l = t & 63, lr = l & 15, g = l >> 4;
  const char* Rb = (const char*)right_t + (size_t)d * 524288;
  const char* Lb = (const char*)left_t  + (size_t)d * 524288;
  f32x4 acc[8][4];
  #pragma unroll
  for (int mi = 0; mi < 8; ++mi)
    #pragma unroll
    for (int nj = 0; nj < 4; ++nj) acc[mi][nj] = (f32x4){0.f, 0.f, 0.f, 0.f};
  const int wm0 = (w >> 2) * 128, wn0 = (w & 3) * 64;
  for (int kb = 0; kb < 512; kb += 64) {
    // stage via global_load_lds: dest = (w*4+cc)*1024 + lane*16 (linear)
    #pragma unroll
    for (int cc = 0; cc < 4; ++cc) {
      const int p16 = (w * 4 + cc) * 64 + l;   // [0,2048)
      const int m = p16 >> 3, sl = p16 & 7;
      __builtin_amdgcn_global_load_lds(
          (const void*)(Rb + (size_t)(i0 + m) * 1024 + kb * 2 + sl * 16),
          (void*)(ldsA + p16 * 16), 16, 0, 0);
      __builtin_amdgcn_global_load_lds(
          (const void*)(Lb + (size_t)(j0 + m) * 1024 + kb * 2 + sl * 16),
          (void*)(ldsB + p16 * 16), 16, 0, 0);
    }
    __syncthreads();
    #pragma unroll
    for (int s = 0; s < 2; ++s) {
      const int soff = (((s * 4 + g) ^ (lr & 7)) << 4);
      bf16x8 af[8], bfr[4];
      #pragma unroll
      for (int mi = 0; mi < 8; ++mi)
        af[mi] = *(const bf16x8*)(ldsA + (wm0 + mi * 16 + lr) * 128 + soff);
      #pragma unroll
      for (int nj = 0; nj < 4; ++nj)
        bfr[nj] = *(const bf16x8*)(ldsB + (wn0 + nj * 16 + lr) * 128 + soff);
      #pragma unroll
      for (int mi = 0; mi < 8; ++mi)
        #pragma unroll
        for (int nj = 0; nj < 4; ++nj)
          acc[mi][nj] = __builtin_amdgcn_mfma_f32_16x16x32_bf16(
              af[mi], bfr[nj], acc[mi][nj], 0, 0, 0);
    }
    __syncthreads();
  }
  // epilogue: two 128-row halves bounced through LDS ([128][544], bank-clean)
  #pragma unroll
  for (int h2 = 0; h2 < 2; ++h2) {
    if ((w >> 2) == h2) {
      #pragma unroll
      for (int mi = 0; mi < 8; ++mi)
        #pragma unroll
        for (int nj = 0; nj < 4; ++nj)
          #pragma unroll
          for (int rr = 0; rr < 4; ++rr) {
            const int rl = mi * 16 + g * 4 + rr;       // local row in half
            const int col = wn0 + nj * 16 + lr;
            *(unsigned short*)(lds + rl * 544 + col * 2) = f2bf(acc[mi][nj][rr]);
          }
    }
    __syncthreads();
    #pragma unroll
    for (int it = 0; it < 8; ++it) {
      const int q = it * 512 + t;                      // [0,4096)
      const int rl = q >> 5, ch = q & 31;
      *(uint4*)((char*)o + (size_t)d * 524288 +
                (size_t)(i0 + h2 * 128 + rl) * 1024 + (size_t)j0 * 2 + ch * 16) =
          *(const uint4*)(lds + rl * 544 + ch * 16);
    }
    __syncthreads();
  }
}

// ---------------- K3: out-LN + out projection + out_gate (fp32 VALU) ---------
// Validated numerics (fp32 LN, fp32 matvec, fp32 W), register-blocked.
// ogate [row][col][d]: contiguous read per position (r5-validated form).
__global__ __launch_bounds__(256) void k3_final(
    const unsigned short* __restrict__ o, const unsigned short* __restrict__ ogate,
    const float* __restrict__ onorm_w, const float* __restrict__ onorm_b,
    const float* __restrict__ out_w, const float* __restrict__ out_b,
    float* __restrict__ out) {
  __shared__ __align__(16) char ldsO[64 * 272];   // [64 d][128 p bf16 + 16B pad]
  __shared__ __align__(16) float ldsW[64 * 68];   // [64 k][64 n + 4 pad] fp32
  __shared__ float sONW[64], sONB[64], sOB[64];
  const int t = threadIdx.x;
  const int i = blockIdx.x >> 2;
  const int j0 = (blockIdx.x & 3) << 7;
  const size_t p0 = (size_t)i * 512 + j0;

  // stage o: 64 rows x 256B (16 chunks each), coalesced
  #pragma unroll
  for (int e = 0; e < 4; ++e) {
    const int u = t + e * 256;       // [0,1024)
    const int d = u >> 4, sl = u & 15;
    *(uint4*)(ldsO + d * 272 + sl * 16) =
        *(const uint4*)((const char*)o + ((size_t)d * 262144 + p0) * 2 + sl * 16);
  }
  // stage out_w fp32 (no rounding): ldsW[k*68+n]
  #pragma unroll
  for (int e = 0; e < 16; ++e) {
    const int idx = e * 256 + t;
    ldsW[(idx >> 6) * 68 + (idx & 63)] = out_w[idx];
  }
  if (t < 64) { sONW[t] = onorm_w[t]; sONB[t] = onorm_b[t]; sOB[t] = out_b[t]; }
  __syncthreads();

  const int p = t >> 1, h = t & 1;
  // LN: column read of 32 channels (bank-rotated by 272B row stride)
  float v[32];
  #pragma unroll
  for (int dl = 0; dl < 32; ++dl)
    v[dl] = bf2f(*(const unsigned short*)(ldsO + (h * 32 + dl) * 272 + p * 2));
  float s = 0.f, ss = 0.f;
  #pragma unroll
  for (int dl = 0; dl < 32; ++dl) { s += v[dl]; ss += v[dl] * v[dl]; }
  s += __shfl_xor(s, 1); ss += __shfl_xor(ss, 1);
  const float mu = s * 0.015625f;
  const float rs = rsqrtf(ss * 0.015625f - mu * mu + 1e-5f);
  float xv[32];
  #pragma unroll
  for (int dl = 0; dl < 32; ++dl) {
    const int d = h * 32 + dl;
    xv[dl] = (v[dl] - mu) * rs * sONW[d] + sONB[d];
  }

  // matvec: out[p][n0..n0+31] = sum_k xn[p][k] * W[k][n]
  const int n0 = h * 32;
  float acc[32];
  #pragma unroll
  for (int n = 0; n < 32; ++n) acc[n] = 0.f;
  #pragma unroll 4
  for (int kk = 0; kk < 32; ++kk) {
    const float a = xv[kk];
    const float* wr = ldsW + (h * 32 + kk) * 68 + n0;
    #pragma unroll
    for (int c = 0; c < 8; ++c) {
      const float4 wv = *(const float4*)(wr + c * 4);
      acc[c*4+0] += a * wv.x; acc[c*4+1] += a * wv.y;
      acc[c*4+2] += a * wv.z; acc[c*4+3] += a * wv.w;
    }
  }
  #pragma unroll 4
  for (int kk = 0; kk < 32; ++kk) {
    const float a = __shfl_xor(xv[kk], 1);
    const float* wr = ldsW + ((1 - h) * 32 + kk) * 68 + n0;
    #pragma unroll
    for (int c = 0; c < 8; ++c) {
      const float4 wv = *(const float4*)(wr + c * 4);
      acc[c*4+0] += a * wv.x; acc[c*4+1] += a * wv.y;
      acc[c*4+2] += a * wv.z; acc[c*4+3] += a * wv.w;
    }
  }

  // epilogue: +out_b, *ogate (bf16, contiguous per position), fp32 store
  const size_t pl = p0 + p;
  const unsigned short* gp = ogate + pl * 64 + n0;
  float* op = out + pl * 64 + n0;
  #pragma unroll
  for (int c = 0; c < 4; ++c) {
    const uint4 g4 = *(const uint4*)(gp + c * 8);
    const unsigned gg[4] = {g4.x, g4.y, g4.z, g4.w};
    float r[8];
    #pragma unroll
    for (int e = 0; e < 4; ++e) {
      r[2*e]   = (acc[c*8 + 2*e]   + sOB[n0 + c*8 + 2*e])   *
                 bf2f((unsigned short)(gg[e] & 0xffffu));
      r[2*e+1] = (acc[c*8 + 2*e+1] + sOB[n0 + c*8 + 2*e+1]) *
                 bf2f((unsigned short)(gg[e] >> 16));
    }
    float4 s0; s0.x = r[0]; s0.y = r[1]; s0.z = r[2]; s0.w = r[3];
    float4 s1; s1.x = r[4]; s1.y = r[5]; s1.z = r[6]; s1.w = r[7];
    *(float4*)(op + c * 8)     = s0;
    *(float4*)(op + c * 8 + 4) = s1;
  }
}

extern "C" void kernel_launch(void* const* d_in, const int* in_sizes, int n_in,
                              void* d_out, int out_size, void* d_ws, size_t ws_size,
                              hipStream_t stream) {
  const float* x       = (const float*)d_in[0];
  const int*   sm      = (const int*)d_in[1];
  const float* norm_w  = (const float*)d_in[2];
  const float* norm_b  = (const float*)d_in[3];
  const float* left_w  = (const float*)d_in[4];
  const float* left_b  = (const float*)d_in[5];
  const float* right_w = (const float*)d_in[6];
  const float* right_b = (const float*)d_in[7];
  const float* lgate_w = (const float*)d_in[8];
  const float* lgate_b = (const float*)d_in[9];
  const float* rgate_w = (const float*)d_in[10];
  const float* rgate_b = (const float*)d_in[11];
  const float* ogate_w = (const float*)d_in[12];
  const float* ogate_b = (const float*)d_in[13];
  const float* onorm_w = (const float*)d_in[14];
  const float* onorm_b = (const float*)d_in[15];
  const float* out_w   = (const float*)d_in[16];
  const float* out_b   = (const float*)d_in[17];

  char* ws = (char*)d_ws;
  unsigned short* left_t  = (unsigned short*)(ws + 0);          // 33.5 MB
  unsigned short* right_t = (unsigned short*)(ws + 33554432);   // 33.5 MB
  unsigned short* ogate   = (unsigned short*)(ws + 67108864);   // 33.5 MB
  unsigned short* obuf    = (unsigned short*)(ws + 100663296);  // 33.5 MB
  unsigned short* wt      = (unsigned short*)(ws + 134217728);  // 40 KB

  if (ws_size < (size_t)134217728 + 40960) return;  // scratch too small

  k0_prep<<<dim3(20), dim3(256), 0, stream>>>(left_w, right_w, lgate_w, rgate_w,
                                              ogate_w, wt);
  k1_proj<<<dim3(2048), dim3(512), 0, stream>>>(x, sm, norm_w, norm_b, left_b,
                                                right_b, lgate_b, rgate_b,
                                                ogate_b, wt, left_t, right_t,
                                                ogate);
  k2_einsum<<<dim3(256), dim3(512), 0, stream>>>(left_t, right_t, obuf);
  k3_final<<<dim3(2048), dim3(256), 0, stream>>>(obuf, ogate, onorm_w, onorm_b,
                                                 out_w, out_b, (float*)d_out);
}

// Round 13
// 121.881 us; speedup vs baseline: 1.1840x; 1.0581x over previous
//
#include <hip/hip_runtime.h>

// TriangleMultiplicativeModule: B=1, L=512, D=H=64, fp32 in/out.
// Pipeline: K0 weight prep -> K1 LN+5 proj (MFMA bf16, LDS-bounced coalesced
// stores) -> K2 einsum (64x batched 512^3 GEMM, MFMA bf16, 256^2 tiles,
// global_load_lds staging, XCD-grouped) -> K3 out-LN + out proj + gate
// (packed-f16 matvec, fp32 flush).
//
// Global bf16 operand layouts are k-contiguous [h][col][k] with a baked XOR
// swizzle on 16B chunks within each 8-chunk (64-elem) window:
//   chunk position q of row holds k-chunk (q ^ (row&7))
// so LDS staging in K2 is a pure linear copy and ds_read_b128 fragment reads
// are bank-conflict-free.
// ogate layout: [row][col][d] (k3 reads contiguous; k1 stores via LDS bounce).

typedef __attribute__((ext_vector_type(4))) float f32x4;
typedef __attribute__((ext_vector_type(8))) __bf16 bf16x8;
typedef __attribute__((ext_vector_type(2))) _Float16 h2;

__device__ __forceinline__ unsigned short f2bf(float f) {
  unsigned u = __float_as_uint(f);
  u += 0x7FFFu + ((u >> 16) & 1u);   // RNE
  return (unsigned short)(u >> 16);
}
__device__ __forceinline__ float bf2f(unsigned short h) {
  return __uint_as_float(((unsigned)h) << 16);
}
// packed pair-convert: compiler lowers __bf16 casts to v_cvt_pk_bf16_f32 (RNE)
__device__ __forceinline__ unsigned pk2bf(float a, float b) {
  unsigned short ua = __builtin_bit_cast(unsigned short, (__bf16)a);
  unsigned short ub = __builtin_bit_cast(unsigned short, (__bf16)b);
  return (unsigned)ua | ((unsigned)ub << 16);
}
__device__ __forceinline__ float sigm(float x) { return 1.0f / (1.0f + __expf(-x)); }

// ---------------- K0: weight prep (20 blocks) ----------------
// wt[320][64] bf16: rows [left|right|lgate|rgate|ogate]; row n holds W[:,ch]
// k-contiguous, 16B chunks swizzled: pos q holds chunk q^(n&7).
__global__ __launch_bounds__(256) void k0_prep(
    const float* __restrict__ lw, const float* __restrict__ rw,
    const float* __restrict__ lgw, const float* __restrict__ rgw,
    const float* __restrict__ ogw, unsigned short* __restrict__ wt) {
  const int t0 = blockIdx.x * 1024 + threadIdx.x;
  #pragma unroll
  for (int e = 0; e < 4; ++e) {
    int idx = t0 + e * 256;  // [0, 20480)
    int n = idx >> 6, k = idx & 63;
    const float* W = (n < 64) ? lw : (n < 128) ? rw : (n < 192) ? lgw
                     : (n < 256) ? rgw : ogw;
    float v = W[k * 64 + (n & 63)];
    int el = n * 64 + ((((k >> 3) ^ (n & 7)) << 3) | (k & 7));
    wt[el] = f2bf(v);
  }
}

// ---------------- K1: LN + 5 projections + gates + mask (r10 form) ----------
// Block: 512 threads (8 waves), 128 positions (rows r0..r0+127 at fixed col c).
// Single-pass 20-frag MFMA. Epilogue bounces results through dead LDS so all
// global stores are dense 16B-per-lane runs.
__global__ __launch_bounds__(512) void k1_proj(
    const float* __restrict__ x, const int* __restrict__ smask,
    const float* __restrict__ norm_w, const float* __restrict__ norm_b,
    const float* __restrict__ left_b, const float* __restrict__ right_b,
    const float* __restrict__ lgate_b, const float* __restrict__ rgate_b,
    const float* __restrict__ ogate_b, const unsigned short* __restrict__ wt,
    unsigned short* __restrict__ left_t, unsigned short* __restrict__ right_t,
    unsigned short* __restrict__ ogate) {
  __shared__ __align__(16) char ldsWt[40960];  // weights; reused as L/R bounce
  __shared__ __align__(16) char ldsX[16384];   // xn swizzled; reused as OG bounce
  __shared__ float sNW[64], sNB[64];
  __shared__ __align__(16) float sLB[64], sRB[64], sLGB[64], sRGB[64], sOGB[64];
  __shared__ float sMK[128];

  const int t = threadIdx.x;
  const int c = blockIdx.x & 511;
  const int r0 = (blockIdx.x >> 9) << 7;

  // stage weights: linear copy (already swizzled in global)
  #pragma unroll
  for (int i = 0; i < 5; ++i) {
    int u = t + i * 512;
    *(uint4*)(ldsWt + u * 16) = *(const uint4*)((const char*)wt + u * 16);
  }
  if (t < 64) {
    sNW[t] = norm_w[t]; sNB[t] = norm_b[t];
    sLB[t] = left_b[t]; sRB[t] = right_b[t];
    sLGB[t] = lgate_b[t]; sRGB[t] = rgate_b[t]; sOGB[t] = ogate_b[t];
  }
  if (t >= 64 && t < 192) sMK[t - 64] = (float)smask[r0 + (t - 64)];
  __syncthreads();

  // phase 1: LayerNorm (4 threads/position, 16 ch each; 128 positions)
  {
    const int m = t >> 2, q = t & 3;
    const float* xp = x + ((size_t)(r0 + m) * 512 + c) * 64 + q * 16;
    float v[16];
    #pragma unroll
    for (int i = 0; i < 4; ++i) {
      float4 f = *(const float4*)(xp + i * 4);
      v[i*4+0] = f.x; v[i*4+1] = f.y; v[i*4+2] = f.z; v[i*4+3] = f.w;
    }
    float s = 0.f, ss = 0.f;
    #pragma unroll
    for (int i = 0; i < 16; ++i) { s += v[i]; ss += v[i] * v[i]; }
    s += __shfl_xor(s, 1); s += __shfl_xor(s, 2);
    ss += __shfl_xor(ss, 1); ss += __shfl_xor(ss, 2);
    const float mu = s * 0.015625f;
    const float rs = rsqrtf(ss * 0.015625f - mu * mu + 1e-5f);
    unsigned pk[8];
    #pragma unroll
    for (int i = 0; i < 8; ++i) {
      const int d0 = q * 16 + 2 * i;
      pk[i] = pk2bf((v[2*i]   - mu) * rs * sNW[d0]     + sNB[d0],
                    (v[2*i+1] - mu) * rs * sNW[d0 + 1] + sNB[d0 + 1]);
    }
    uint4 lo; lo.x = pk[0]; lo.y = pk[1]; lo.z = pk[2]; lo.w = pk[3];
    uint4 hi; hi.x = pk[4]; hi.y = pk[5]; hi.z = pk[6]; hi.w = pk[7];
    *(uint4*)(ldsX + m * 128 + (((q * 2)     ^ (m & 7)) << 4)) = lo;
    *(uint4*)(ldsX + m * 128 + (((q * 2 + 1) ^ (m & 7)) << 4)) = hi;
  }
  __syncthreads();

  // phase 2: MFMA  out[m][n] = xn[m][k] @ W[k][n], n in [0,320)
  // nf 0..15: D[pos][n] (A=xn, B=W). nf 16..19 (ogate): SWAPPED -> D[d][pos].
  const int w = t >> 6, l = t & 63, lr = l & 15, g = l >> 4;
  f32x4 acc[20];
  #pragma unroll
  for (int nf = 0; nf < 20; ++nf) acc[nf] = (f32x4){0.f, 0.f, 0.f, 0.f};
  const int rowA = w * 16 + lr;
  #pragma unroll
  for (int s = 0; s < 2; ++s) {
    const int soff = (((s * 4 + g) ^ (lr & 7)) << 4);
    bf16x8 a = *(const bf16x8*)(ldsX + rowA * 128 + soff);
    #pragma unroll
    for (int nf = 0; nf < 16; ++nf) {
      bf16x8 bb = *(const bf16x8*)(ldsWt + (nf * 16 + lr) * 128 + soff);
      acc[nf] = __builtin_amdgcn_mfma_f32_16x16x32_bf16(a, bb, acc[nf], 0, 0, 0);
    }
    #pragma unroll
    for (int nf = 16; nf < 20; ++nf) {
      bf16x8 bb = *(const bf16x8*)(ldsWt + (nf * 16 + lr) * 128 + soff);
      acc[nf] = __builtin_amdgcn_mfma_f32_16x16x32_bf16(bb, a, acc[nf], 0, 0, 0);
    }
  }
  __syncthreads();   // all MFMA LDS reads done -> ldsWt/ldsX reusable

  // epilogue compute -> LDS bounce
  char* bL = ldsWt;            // [64 ch][272B] (128 pos bf16 + 16B pad)
  char* bR = ldsWt + 17408;    // [64 ch][272B]
  {
    const float mc = (float)smask[c];
    float mk[4];
    #pragma unroll
    for (int rr = 0; rr < 4; ++rr) mk[rr] = mc * sMK[w * 16 + g * 4 + rr];
    const int rb2 = (w * 16 + g * 4) * 2;
    #pragma unroll
    for (int nf = 0; nf < 4; ++nf) {
      const int hh = nf * 16 + lr;
      const float lb = sLB[hh], rb = sRB[hh];
      const float lgb = sLGB[hh], rgb = sRGB[hh];
      float lo[4], ro[4];
      #pragma unroll
      for (int rr = 0; rr < 4; ++rr) {
        lo[rr] = (acc[nf][rr]     + lb) * mk[rr] * sigm(acc[8  + nf][rr] + lgb);
        ro[rr] = (acc[4 + nf][rr] + rb) * mk[rr] * sigm(acc[12 + nf][rr] + rgb);
      }
      uint2 lv; lv.x = pk2bf(lo[0], lo[1]); lv.y = pk2bf(lo[2], lo[3]);
      uint2 rv; rv.x = pk2bf(ro[0], ro[1]); rv.y = pk2bf(ro[2], ro[3]);
      *(uint2*)(bL + hh * 272 + rb2) = lv;
      *(uint2*)(bR + hh * 272 + rb2) = rv;
    }
    // ogate bounce: [128 r][64 d] in ldsX, 16B chunks XOR-swizzled by (r&7)
    const int rloc = w * 16 + lr;
    #pragma unroll
    for (int nf = 0; nf < 4; ++nf) {
      const int d0 = nf * 16 + g * 4;
      const float4 ob4 = *(const float4*)&sOGB[d0];
      const float g0 = sigm(acc[16 + nf][0] + ob4.x);
      const float g1 = sigm(acc[16 + nf][1] + ob4.y);
      const float g2 = sigm(acc[16 + nf][2] + ob4.z);
      const float g3 = sigm(acc[16 + nf][3] + ob4.w);
      uint2 gv; gv.x = pk2bf(g0, g1); gv.y = pk2bf(g2, g3);
      const int slot = (d0 >> 3) ^ (rloc & 7);
      *(uint2*)(ldsX + rloc * 128 + slot * 16 + (d0 & 4) * 2) = gv;
    }
  }
  __syncthreads();

  // coalesced stores: dense 16B per lane
  const int cx = c & 7;
  #pragma unroll
  for (int it = 0; it < 2; ++it) {
    const int idx = it * 512 + t;            // [0,1024)
    const int hh = idx >> 4, rel = idx & 15;
    const size_t goff = (size_t)hh * 524288 + (size_t)c * 1024 +
                        (size_t)(((r0 >> 3) + (rel & 8) + ((rel & 7) ^ cx)) << 4);
    *(uint4*)((char*)left_t  + goff) = *(const uint4*)(bL + hh * 272 + rel * 16);
    *(uint4*)((char*)right_t + goff) = *(const uint4*)(bR + hh * 272 + rel * 16);
  }
  // ogate -> [row][col][d]: per row a contiguous 128B run (8 chunks)
  #pragma unroll
  for (int it = 0; it < 2; ++it) {
    const int idx = it * 512 + t;            // [0,1024)
    const int rl = idx >> 3, ch = idx & 7;
    *(uint4*)((char*)ogate + ((size_t)(r0 + rl) * 512 + c) * 128 + ch * 16) =
        *(const uint4*)(ldsX + rl * 128 + ((ch ^ (rl & 7)) << 4));
  }
}

// ---------------- K2: einsum  o[d][i][j] = sum_k right_t[d][i][k]*left_t[d][j][k]
// 256x256 tiles. global_load_lds staging (linear dest = wave base + lane*16).
// XCD grouping: same-d quadrants dispatch to one XCD (share operand panels in
// its L2). Epilogue: bounce 128-row halves through dead LDS -> 16B stores in
// 512B segments instead of 128 scalar 2B scatters.
__global__ __launch_bounds__(512) void k2_einsum(
    const unsigned short* __restrict__ left_t,
    const unsigned short* __restrict__ right_t,
    unsigned short* __restrict__ o) {
  __shared__ __align__(16) char lds[69632];   // A[0:32K] B[32K:64K]; bounce [128][544]
  char* ldsA = lds;
  char* ldsB = lds + 32768;
  const int t = threadIdx.x;
  const int bid = (int)blockIdx.x;
  const int id = ((bid & 7) << 5) | (bid >> 3);  // round-robin slot -> XCD group
  const int d = id >> 2;
  const int i0 = ((id >> 1) & 1) * 256;
  const int j0 = (id & 1) * 256;
  const int w = t >> 6, l = t & 63, lr = l & 15, g = l >> 4;
  const char* Rb = (const char*)right_t + (size_t)d * 524288;
  const char* Lb = (const char*)left_t  + (size_t)d * 524288;
  f32x4 acc[8][4];
  #pragma unroll
  for (int mi = 0; mi < 8; ++mi)
    #pragma unroll
    for (int nj = 0; nj < 4; ++nj) acc[mi][nj] = (f32x4){0.f, 0.f, 0.f, 0.f};
  const int wm0 = (w >> 2) * 128, wn0 = (w & 3) * 64;
  for (int kb = 0; kb < 512; kb += 64) {
    // stage via global_load_lds: dest = (w*4+cc)*1024 + lane*16 (linear)
    #pragma unroll
    for (int cc = 0; cc < 4; ++cc) {
      const int p16 = (w * 4 + cc) * 64 + l;   // [0,2048)
      const int m = p16 >> 3, sl = p16 & 7;
      __builtin_amdgcn_global_load_lds(
          (const void*)(Rb + (size_t)(i0 + m) * 1024 + kb * 2 + sl * 16),
          (void*)(ldsA + p16 * 16), 16, 0, 0);
      __builtin_amdgcn_global_load_lds(
          (const void*)(Lb + (size_t)(j0 + m) * 1024 + kb * 2 + sl * 16),
          (void*)(ldsB + p16 * 16), 16, 0, 0);
    }
    __syncthreads();
    #pragma unroll
    for (int s = 0; s < 2; ++s) {
      const int soff = (((s * 4 + g) ^ (lr & 7)) << 4);
      bf16x8 af[8], bfr[4];
      #pragma unroll
      for (int mi = 0; mi < 8; ++mi)
        af[mi] = *(const bf16x8*)(ldsA + (wm0 + mi * 16 + lr) * 128 + soff);
      #pragma unroll
      for (int nj = 0; nj < 4; ++nj)
        bfr[nj] = *(const bf16x8*)(ldsB + (wn0 + nj * 16 + lr) * 128 + soff);
      #pragma unroll
      for (int mi = 0; mi < 8; ++mi)
        #pragma unroll
        for (int nj = 0; nj < 4; ++nj)
          acc[mi][nj] = __builtin_amdgcn_mfma_f32_16x16x32_bf16(
              af[mi], bfr[nj], acc[mi][nj], 0, 0, 0);
    }
    __syncthreads();
  }
  // epilogue: two 128-row halves bounced through LDS ([128][544], bank-clean)
  #pragma unroll
  for (int h2i = 0; h2i < 2; ++h2i) {
    if ((w >> 2) == h2i) {
      #pragma unroll
      for (int mi = 0; mi < 8; ++mi)
        #pragma unroll
        for (int nj = 0; nj < 4; ++nj)
          #pragma unroll
          for (int rr = 0; rr < 4; ++rr) {
            const int rl = mi * 16 + g * 4 + rr;       // local row in half
            const int col = wn0 + nj * 16 + lr;
            *(unsigned short*)(lds + rl * 544 + col * 2) = f2bf(acc[mi][nj][rr]);
          }
    }
    __syncthreads();
    #pragma unroll
    for (int it = 0; it < 8; ++it) {
      const int q = it * 512 + t;                      // [0,4096)
      const int rl = q >> 5, ch = q & 31;
      *(uint4*)((char*)o + (size_t)d * 524288 +
                (size_t)(i0 + h2i * 128 + rl) * 1024 + (size_t)j0 * 2 + ch * 16) =
          *(const uint4*)(lds + rl * 544 + ch * 16);
    }
    __syncthreads();
  }
}

// ---------------- K3: out-LN + out projection + out_gate ---------------------
// Validated staging/LN/epilogue (r5 form); matvec now packed-f16 v_pk_fma_f16
// with fp32 flush every 16 k (accumulation drift bounded ~1.7e-3 worst-tail).
__global__ __launch_bounds__(256) void k3_final(
    const unsigned short* __restrict__ o, const unsigned short* __restrict__ ogate,
    const float* __restrict__ onorm_w, const float* __restrict__ onorm_b,
    const float* __restrict__ out_w, const float* __restrict__ out_b,
    float* __restrict__ out) {
  __shared__ __align__(16) char ldsO[64 * 272];       // [64 d][128 p bf16 + pad]
  __shared__ __align__(16) _Float16 ldsW[64 * 72];    // [64 k][64 n + 8 pad] f16
  __shared__ float sONW[64], sONB[64], sOB[64];
  const int t = threadIdx.x;
  const int i = blockIdx.x >> 2;
  const int j0 = (blockIdx.x & 3) << 7;
  const size_t p0 = (size_t)i * 512 + j0;

  // stage o: 64 rows x 256B (16 chunks each), coalesced
  #pragma unroll
  for (int e = 0; e < 4; ++e) {
    const int u = t + e * 256;       // [0,1024)
    const int d = u >> 4, sl = u & 15;
    *(uint4*)(ldsO + d * 272 + sl * 16) =
        *(const uint4*)((const char*)o + ((size_t)d * 262144 + p0) * 2 + sl * 16);
  }
  // stage out_w as f16: ldsW[k*72+n]  (RNE; f16 rel err 2^-11, negligible)
  #pragma unroll
  for (int e = 0; e < 16; ++e) {
    const int idx = e * 256 + t;
    ldsW[(idx >> 6) * 72 + (idx & 63)] = (_Float16)out_w[idx];
  }
  if (t < 64) { sONW[t] = onorm_w[t]; sONB[t] = onorm_b[t]; sOB[t] = out_b[t]; }
  __syncthreads();

  const int p = t >> 1, h = t & 1;
  // LN: column read of 32 channels (bank-rotated by 272B row stride)
  float v[32];
  #pragma unroll
  for (int dl = 0; dl < 32; ++dl)
    v[dl] = bf2f(*(const unsigned short*)(ldsO + (h * 32 + dl) * 272 + p * 2));
  float s = 0.f, ss = 0.f;
  #pragma unroll
  for (int dl = 0; dl < 32; ++dl) { s += v[dl]; ss += v[dl] * v[dl]; }
  s += __shfl_xor(s, 1); ss += __shfl_xor(ss, 1);
  const float mu = s * 0.015625f;
  const float rs = rsqrtf(ss * 0.015625f - mu * mu + 1e-5f);
  float xv[32];
  #pragma unroll
  for (int dl = 0; dl < 32; ++dl) {
    const int d = h * 32 + dl;
    xv[dl] = (v[dl] - mu) * rs * sONW[d] + sONB[d];
  }

  // matvec: out[p][n0..n0+31] = sum_k xn[p][k] * W[k][n], packed f16
  const int n0 = h * 32;
  _Float16 xA[32], xB[32];   // own k-half / partner k-half (static indexing)
  #pragma unroll
  for (int dl = 0; dl < 32; ++dl) {
    xA[dl] = (_Float16)xv[dl];
    xB[dl] = (_Float16)__shfl_xor(xv[dl], 1);
  }
  float acc[32];
  #pragma unroll
  for (int n = 0; n < 32; ++n) acc[n] = 0.f;
  const int kO = h * 32, kP = (1 - h) * 32;
  #pragma unroll
  for (int pb = 0; pb < 4; ++pb) {       // pb 0,1: own half; 2,3: partner half
    h2 acc2[16];
    #pragma unroll
    for (int n2 = 0; n2 < 16; ++n2) { acc2[n2][0] = (_Float16)0.f; acc2[n2][1] = (_Float16)0.f; }
    #pragma unroll
    for (int kk = 0; kk < 16; ++kk) {
      const int ko = (pb & 1) * 16 + kk;                 // compile-time
      const _Float16 av = (pb < 2) ? xA[ko] : xB[ko];    // compile-time select
      const int k = ((pb < 2) ? kO : kP) + ko;
      h2 a2; a2[0] = av; a2[1] = av;
      const uint4* wr = (const uint4*)(ldsW + k * 72 + n0);  // 144B rows, 16B-aligned
      const uint4 w0 = wr[0], w1 = wr[1], w2 = wr[2], w3 = wr[3];
      const unsigned wu[16] = {w0.x, w0.y, w0.z, w0.w, w1.x, w1.y, w1.z, w1.w,
                               w2.x, w2.y, w2.z, w2.w, w3.x, w3.y, w3.z, w3.w};
      #pragma unroll
      for (int n2 = 0; n2 < 16; ++n2)
        acc2[n2] = a2 * __builtin_bit_cast(h2, wu[n2]) + acc2[n2];  // v_pk_fma_f16
    }
    #pragma unroll
    for (int n2 = 0; n2 < 16; ++n2) {       // fp32 flush every 16 k
      acc[2 * n2]     += (float)acc2[n2][0];
      acc[2 * n2 + 1] += (float)acc2[n2][1];
    }
  }

  // epilogue: +out_b, *ogate (bf16, contiguous per position), fp32 store
  const size_t pl = p0 + p;
  const unsigned short* gp = ogate + pl * 64 + n0;
  float* op = out + pl * 64 + n0;
  #pragma unroll
  for (int c = 0; c < 4; ++c) {
    const uint4 g4 = *(const uint4*)(gp + c * 8);
    const unsigned gg[4] = {g4.x, g4.y, g4.z, g4.w};
    float r[8];
    #pragma unroll
    for (int e = 0; e < 4; ++e) {
      r[2*e]   = (acc[c*8 + 2*e]   + sOB[n0 + c*8 + 2*e])   *
                 bf2f((unsigned short)(gg[e] & 0xffffu));
      r[2*e+1] = (acc[c*8 + 2*e+1] + sOB[n0 + c*8 + 2*e+1]) *
                 bf2f((unsigned short)(gg[e] >> 16));
    }
    float4 s0; s0.x = r[0]; s0.y = r[1]; s0.z = r[2]; s0.w = r[3];
    float4 s1; s1.x = r[4]; s1.y = r[5]; s1.z = r[6]; s1.w = r[7];
    *(float4*)(op + c * 8)     = s0;
    *(float4*)(op + c * 8 + 4) = s1;
  }
}

extern "C" void kernel_launch(void* const* d_in, const int* in_sizes, int n_in,
                              void* d_out, int out_size, void* d_ws, size_t ws_size,
                              hipStream_t stream) {
  const float* x       = (const float*)d_in[0];
  const int*   sm      = (const int*)d_in[1];
  const float* norm_w  = (const float*)d_in[2];
  const float* norm_b  = (const float*)d_in[3];
  const float* left_w  = (const float*)d_in[4];
  const float* left_b  = (const float*)d_in[5];
  const float* right_w = (const float*)d_in[6];
  const float* right_b = (const float*)d_in[7];
  const float* lgate_w = (const float*)d_in[8];
  const float* lgate_b = (const float*)d_in[9];
  const float* rgate_w = (const float*)d_in[10];
  const float* rgate_b = (const float*)d_in[11];
  const float* ogate_w = (const float*)d_in[12];
  const float* ogate_b = (const float*)d_in[13];
  const float* onorm_w = (const float*)d_in[14];
  const float* onorm_b = (const float*)d_in[15];
  const float* out_w   = (const float*)d_in[16];
  const float* out_b   = (const float*)d_in[17];

  char* ws = (char*)d_ws;
  unsigned short* left_t  = (unsigned short*)(ws + 0);          // 33.5 MB
  unsigned short* right_t = (unsigned short*)(ws + 33554432);   // 33.5 MB
  unsigned short* ogate   = (unsigned short*)(ws + 67108864);   // 33.5 MB
  unsigned short* obuf    = (unsigned short*)(ws + 100663296);  // 33.5 MB
  unsigned short* wt      = (unsigned short*)(ws + 134217728);  // 40 KB

  if (ws_size < (size_t)134217728 + 40960) return;  // scratch too small

  k0_prep<<<dim3(20), dim3(256), 0, stream>>>(left_w, right_w, lgate_w, rgate_w,
                                              ogate_w, wt);
  k1_proj<<<dim3(2048), dim3(512), 0, stream>>>(x, sm, norm_w, norm_b, left_b,
                                                right_b, lgate_b, rgate_b,
                                                ogate_b, wt, left_t, right_t,
                                                ogate);
  k2_einsum<<<dim3(256), dim3(512), 0, stream>>>(left_t, right_t, obuf);
  k3_final<<<dim3(2048), dim3(256), 0, stream>>>(obuf, ogate, onorm_w, onorm_b,
                                                 out_w, out_b, (float*)d_out);
}

// Round 14
// 120.781 us; speedup vs baseline: 1.1948x; 1.0091x over previous
//
#include <hip/hip_runtime.h>

// TriangleMultiplicativeModule: B=1, L=512, D=H=64, fp32 in/out.
// Pipeline: K0 weight prep -> K1 LN+5 proj (MFMA bf16, LDS-bounced coalesced
// stores) -> K2 einsum (64x batched 512^3 GEMM, MFMA bf16, 256^2 tiles,
// global_load_lds staging, XCD-grouped) -> K3 out-LN + out proj + gate
// (direct-global LN reads, packed-f16 matvec, fp32 flush).
//
// Global bf16 operand layouts are k-contiguous [h][col][k] with a baked XOR
// swizzle on 16B chunks within each 8-chunk (64-elem) window:
//   chunk position q of row holds k-chunk (q ^ (row&7))
// so LDS staging in K2 is a pure linear copy and ds_read_b128 fragment reads
// are bank-conflict-free.
// ogate layout: [row][col][d] (k3 reads contiguous; k1 stores via LDS bounce).

typedef __attribute__((ext_vector_type(4))) float f32x4;
typedef __attribute__((ext_vector_type(8))) __bf16 bf16x8;
typedef __attribute__((ext_vector_type(2))) _Float16 h2;

__device__ __forceinline__ unsigned short f2bf(float f) {
  unsigned u = __float_as_uint(f);
  u += 0x7FFFu + ((u >> 16) & 1u);   // RNE
  return (unsigned short)(u >> 16);
}
__device__ __forceinline__ float bf2f(unsigned short h) {
  return __uint_as_float(((unsigned)h) << 16);
}
// packed pair-convert: compiler lowers __bf16 casts to v_cvt_pk_bf16_f32 (RNE)
__device__ __forceinline__ unsigned pk2bf(float a, float b) {
  unsigned short ua = __builtin_bit_cast(unsigned short, (__bf16)a);
  unsigned short ub = __builtin_bit_cast(unsigned short, (__bf16)b);
  return (unsigned)ua | ((unsigned)ub << 16);
}
__device__ __forceinline__ float sigm(float x) { return 1.0f / (1.0f + __expf(-x)); }

// ---------------- K0: weight prep (20 blocks) ----------------
// wt[320][64] bf16: rows [left|right|lgate|rgate|ogate]; row n holds W[:,ch]
// k-contiguous, 16B chunks swizzled: pos q holds chunk q^(n&7).
__global__ __launch_bounds__(256) void k0_prep(
    const float* __restrict__ lw, const float* __restrict__ rw,
    const float* __restrict__ lgw, const float* __restrict__ rgw,
    const float* __restrict__ ogw, unsigned short* __restrict__ wt) {
  const int t0 = blockIdx.x * 1024 + threadIdx.x;
  #pragma unroll
  for (int e = 0; e < 4; ++e) {
    int idx = t0 + e * 256;  // [0, 20480)
    int n = idx >> 6, k = idx & 63;
    const float* W = (n < 64) ? lw : (n < 128) ? rw : (n < 192) ? lgw
                     : (n < 256) ? rgw : ogw;
    float v = W[k * 64 + (n & 63)];
    int el = n * 64 + ((((k >> 3) ^ (n & 7)) << 3) | (k & 7));
    wt[el] = f2bf(v);
  }
}

// ---------------- K1: LN + 5 projections + gates + mask (r10 form) ----------
// Block: 512 threads (8 waves), 128 positions (rows r0..r0+127 at fixed col c).
// Single-pass 20-frag MFMA. Epilogue bounces results through dead LDS so all
// global stores are dense 16B-per-lane runs.
__global__ __launch_bounds__(512) void k1_proj(
    const float* __restrict__ x, const int* __restrict__ smask,
    const float* __restrict__ norm_w, const float* __restrict__ norm_b,
    const float* __restrict__ left_b, const float* __restrict__ right_b,
    const float* __restrict__ lgate_b, const float* __restrict__ rgate_b,
    const float* __restrict__ ogate_b, const unsigned short* __restrict__ wt,
    unsigned short* __restrict__ left_t, unsigned short* __restrict__ right_t,
    unsigned short* __restrict__ ogate) {
  __shared__ __align__(16) char ldsWt[40960];  // weights; reused as L/R bounce
  __shared__ __align__(16) char ldsX[16384];   // xn swizzled; reused as OG bounce
  __shared__ float sNW[64], sNB[64];
  __shared__ __align__(16) float sLB[64], sRB[64], sLGB[64], sRGB[64], sOGB[64];
  __shared__ float sMK[128];

  const int t = threadIdx.x;
  const int c = blockIdx.x & 511;
  const int r0 = (blockIdx.x >> 9) << 7;

  // stage weights: linear copy (already swizzled in global)
  #pragma unroll
  for (int i = 0; i < 5; ++i) {
    int u = t + i * 512;
    *(uint4*)(ldsWt + u * 16) = *(const uint4*)((const char*)wt + u * 16);
  }
  if (t < 64) {
    sNW[t] = norm_w[t]; sNB[t] = norm_b[t];
    sLB[t] = left_b[t]; sRB[t] = right_b[t];
    sLGB[t] = lgate_b[t]; sRGB[t] = rgate_b[t]; sOGB[t] = ogate_b[t];
  }
  if (t >= 64 && t < 192) sMK[t - 64] = (float)smask[r0 + (t - 64)];
  __syncthreads();

  // phase 1: LayerNorm (4 threads/position, 16 ch each; 128 positions)
  {
    const int m = t >> 2, q = t & 3;
    const float* xp = x + ((size_t)(r0 + m) * 512 + c) * 64 + q * 16;
    float v[16];
    #pragma unroll
    for (int i = 0; i < 4; ++i) {
      float4 f = *(const float4*)(xp + i * 4);
      v[i*4+0] = f.x; v[i*4+1] = f.y; v[i*4+2] = f.z; v[i*4+3] = f.w;
    }
    float s = 0.f, ss = 0.f;
    #pragma unroll
    for (int i = 0; i < 16; ++i) { s += v[i]; ss += v[i] * v[i]; }
    s += __shfl_xor(s, 1); s += __shfl_xor(s, 2);
    ss += __shfl_xor(ss, 1); ss += __shfl_xor(ss, 2);
    const float mu = s * 0.015625f;
    const float rs = rsqrtf(ss * 0.015625f - mu * mu + 1e-5f);
    unsigned pk[8];
    #pragma unroll
    for (int i = 0; i < 8; ++i) {
      const int d0 = q * 16 + 2 * i;
      pk[i] = pk2bf((v[2*i]   - mu) * rs * sNW[d0]     + sNB[d0],
                    (v[2*i+1] - mu) * rs * sNW[d0 + 1] + sNB[d0 + 1]);
    }
    uint4 lo; lo.x = pk[0]; lo.y = pk[1]; lo.z = pk[2]; lo.w = pk[3];
    uint4 hi; hi.x = pk[4]; hi.y = pk[5]; hi.z = pk[6]; hi.w = pk[7];
    *(uint4*)(ldsX + m * 128 + (((q * 2)     ^ (m & 7)) << 4)) = lo;
    *(uint4*)(ldsX + m * 128 + (((q * 2 + 1) ^ (m & 7)) << 4)) = hi;
  }
  __syncthreads();

  // phase 2: MFMA  out[m][n] = xn[m][k] @ W[k][n], n in [0,320)
  // nf 0..15: D[pos][n] (A=xn, B=W). nf 16..19 (ogate): SWAPPED -> D[d][pos].
  const int w = t >> 6, l = t & 63, lr = l & 15, g = l >> 4;
  f32x4 acc[20];
  #pragma unroll
  for (int nf = 0; nf < 20; ++nf) acc[nf] = (f32x4){0.f, 0.f, 0.f, 0.f};
  const int rowA = w * 16 + lr;
  #pragma unroll
  for (int s = 0; s < 2; ++s) {
    const int soff = (((s * 4 + g) ^ (lr & 7)) << 4);
    bf16x8 a = *(const bf16x8*)(ldsX + rowA * 128 + soff);
    #pragma unroll
    for (int nf = 0; nf < 16; ++nf) {
      bf16x8 bb = *(const bf16x8*)(ldsWt + (nf * 16 + lr) * 128 + soff);
      acc[nf] = __builtin_amdgcn_mfma_f32_16x16x32_bf16(a, bb, acc[nf], 0, 0, 0);
    }
    #pragma unroll
    for (int nf = 16; nf < 20; ++nf) {
      bf16x8 bb = *(const bf16x8*)(ldsWt + (nf * 16 + lr) * 128 + soff);
      acc[nf] = __builtin_amdgcn_mfma_f32_16x16x32_bf16(bb, a, acc[nf], 0, 0, 0);
    }
  }
  __syncthreads();   // all MFMA LDS reads done -> ldsWt/ldsX reusable

  // epilogue compute -> LDS bounce
  char* bL = ldsWt;            // [64 ch][272B] (128 pos bf16 + 16B pad)
  char* bR = ldsWt + 17408;    // [64 ch][272B]
  {
    const float mc = (float)smask[c];
    float mk[4];
    #pragma unroll
    for (int rr = 0; rr < 4; ++rr) mk[rr] = mc * sMK[w * 16 + g * 4 + rr];
    const int rb2 = (w * 16 + g * 4) * 2;
    #pragma unroll
    for (int nf = 0; nf < 4; ++nf) {
      const int hh = nf * 16 + lr;
      const float lb = sLB[hh], rb = sRB[hh];
      const float lgb = sLGB[hh], rgb = sRGB[hh];
      float lo[4], ro[4];
      #pragma unroll
      for (int rr = 0; rr < 4; ++rr) {
        lo[rr] = (acc[nf][rr]     + lb) * mk[rr] * sigm(acc[8  + nf][rr] + lgb);
        ro[rr] = (acc[4 + nf][rr] + rb) * mk[rr] * sigm(acc[12 + nf][rr] + rgb);
      }
      uint2 lv; lv.x = pk2bf(lo[0], lo[1]); lv.y = pk2bf(lo[2], lo[3]);
      uint2 rv; rv.x = pk2bf(ro[0], ro[1]); rv.y = pk2bf(ro[2], ro[3]);
      *(uint2*)(bL + hh * 272 + rb2) = lv;
      *(uint2*)(bR + hh * 272 + rb2) = rv;
    }
    // ogate bounce: [128 r][64 d] in ldsX, 16B chunks XOR-swizzled by (r&7)
    const int rloc = w * 16 + lr;
    #pragma unroll
    for (int nf = 0; nf < 4; ++nf) {
      const int d0 = nf * 16 + g * 4;
      const float4 ob4 = *(const float4*)&sOGB[d0];
      const float g0 = sigm(acc[16 + nf][0] + ob4.x);
      const float g1 = sigm(acc[16 + nf][1] + ob4.y);
      const float g2 = sigm(acc[16 + nf][2] + ob4.z);
      const float g3 = sigm(acc[16 + nf][3] + ob4.w);
      uint2 gv; gv.x = pk2bf(g0, g1); gv.y = pk2bf(g2, g3);
      const int slot = (d0 >> 3) ^ (rloc & 7);
      *(uint2*)(ldsX + rloc * 128 + slot * 16 + (d0 & 4) * 2) = gv;
    }
  }
  __syncthreads();

  // coalesced stores: dense 16B per lane
  const int cx = c & 7;
  #pragma unroll
  for (int it = 0; it < 2; ++it) {
    const int idx = it * 512 + t;            // [0,1024)
    const int hh = idx >> 4, rel = idx & 15;
    const size_t goff = (size_t)hh * 524288 + (size_t)c * 1024 +
                        (size_t)(((r0 >> 3) + (rel & 8) + ((rel & 7) ^ cx)) << 4);
    *(uint4*)((char*)left_t  + goff) = *(const uint4*)(bL + hh * 272 + rel * 16);
    *(uint4*)((char*)right_t + goff) = *(const uint4*)(bR + hh * 272 + rel * 16);
  }
  // ogate -> [row][col][d]: per row a contiguous 128B run (8 chunks)
  #pragma unroll
  for (int it = 0; it < 2; ++it) {
    const int idx = it * 512 + t;            // [0,1024)
    const int rl = idx >> 3, ch = idx & 7;
    *(uint4*)((char*)ogate + ((size_t)(r0 + rl) * 512 + c) * 128 + ch * 16) =
        *(const uint4*)(ldsX + rl * 128 + ((ch ^ (rl & 7)) << 4));
  }
}

// ---------------- K2: einsum  o[d][i][j] = sum_k right_t[d][i][k]*left_t[d][j][k]
// 256x256 tiles. global_load_lds staging (linear dest = wave base + lane*16).
// XCD grouping: same-d quadrants dispatch to one XCD (share operand panels in
// its L2). Epilogue: bounce 128-row halves through dead LDS -> 16B stores in
// 512B segments instead of 128 scalar 2B scatters.
__global__ __launch_bounds__(512) void k2_einsum(
    const unsigned short* __restrict__ left_t,
    const unsigned short* __restrict__ right_t,
    unsigned short* __restrict__ o) {
  __shared__ __align__(16) char lds[69632];   // A[0:32K] B[32K:64K]; bounce [128][544]
  char* ldsA = lds;
  char* ldsB = lds + 32768;
  const int t = threadIdx.x;
  const int bid = (int)blockIdx.x;
  const int id = ((bid & 7) << 5) | (bid >> 3);  // round-robin slot -> XCD group
  const int d = id >> 2;
  const int i0 = ((id >> 1) & 1) * 256;
  const int j0 = (id & 1) * 256;
  const int w = t >> 6, l = t & 63, lr = l & 15, g = l >> 4;
  const char* Rb = (const char*)right_t + (size_t)d * 524288;
  const char* Lb = (const char*)left_t  + (size_t)d * 524288;
  f32x4 acc[8][4];
  #pragma unroll
  for (int mi = 0; mi < 8; ++mi)
    #pragma unroll
    for (int nj = 0; nj < 4; ++nj) acc[mi][nj] = (f32x4){0.f, 0.f, 0.f, 0.f};
  const int wm0 = (w >> 2) * 128, wn0 = (w & 3) * 64;
  for (int kb = 0; kb < 512; kb += 64) {
    // stage via global_load_lds: dest = (w*4+cc)*1024 + lane*16 (linear)
    #pragma unroll
    for (int cc = 0; cc < 4; ++cc) {
      const int p16 = (w * 4 + cc) * 64 + l;   // [0,2048)
      const int m = p16 >> 3, sl = p16 & 7;
      __builtin_amdgcn_global_load_lds(
          (const void*)(Rb + (size_t)(i0 + m) * 1024 + kb * 2 + sl * 16),
          (void*)(ldsA + p16 * 16), 16, 0, 0);
      __builtin_amdgcn_global_load_lds(
          (const void*)(Lb + (size_t)(j0 + m) * 1024 + kb * 2 + sl * 16),
          (void*)(ldsB + p16 * 16), 16, 0, 0);
    }
    __syncthreads();
    #pragma unroll
    for (int s = 0; s < 2; ++s) {
      const int soff = (((s * 4 + g) ^ (lr & 7)) << 4);
      bf16x8 af[8], bfr[4];
      #pragma unroll
      for (int mi = 0; mi < 8; ++mi)
        af[mi] = *(const bf16x8*)(ldsA + (wm0 + mi * 16 + lr) * 128 + soff);
      #pragma unroll
      for (int nj = 0; nj < 4; ++nj)
        bfr[nj] = *(const bf16x8*)(ldsB + (wn0 + nj * 16 + lr) * 128 + soff);
      #pragma unroll
      for (int mi = 0; mi < 8; ++mi)
        #pragma unroll
        for (int nj = 0; nj < 4; ++nj)
          acc[mi][nj] = __builtin_amdgcn_mfma_f32_16x16x32_bf16(
              af[mi], bfr[nj], acc[mi][nj], 0, 0, 0);
    }
    __syncthreads();
  }
  // epilogue: two 128-row halves bounced through LDS ([128][544], bank-clean)
  #pragma unroll
  for (int h2i = 0; h2i < 2; ++h2i) {
    if ((w >> 2) == h2i) {
      #pragma unroll
      for (int mi = 0; mi < 8; ++mi)
        #pragma unroll
        for (int nj = 0; nj < 4; ++nj)
          #pragma unroll
          for (int rr = 0; rr < 4; ++rr) {
            const int rl = mi * 16 + g * 4 + rr;       // local row in half
            const int col = wn0 + nj * 16 + lr;
            *(unsigned short*)(lds + rl * 544 + col * 2) = f2bf(acc[mi][nj][rr]);
          }
    }
    __syncthreads();
    #pragma unroll
    for (int it = 0; it < 8; ++it) {
      const int q = it * 512 + t;                      // [0,4096)
      const int rl = q >> 5, ch = q & 31;
      *(uint4*)((char*)o + (size_t)d * 524288 +
                (size_t)(i0 + h2i * 128 + rl) * 1024 + (size_t)j0 * 2 + ch * 16) =
          *(const uint4*)(lds + rl * 544 + ch * 16);
    }
    __syncthreads();
  }
}

// ---------------- K3: out-LN + out projection + out_gate ---------------------
// Direct-global LN reads (bit-identical values; 64B coalesced segments per
// d-plane, L3-resident, hoisted above W staging). No ldsO -> LDS ~10KB ->
// 8 blocks/CU static. Packed-f16 matvec with fp32 flush every 16 k.
__global__ __launch_bounds__(256) void k3_final(
    const unsigned short* __restrict__ o, const unsigned short* __restrict__ ogate,
    const float* __restrict__ onorm_w, const float* __restrict__ onorm_b,
    const float* __restrict__ out_w, const float* __restrict__ out_b,
    float* __restrict__ out) {
  __shared__ __align__(16) _Float16 ldsW[64 * 72];    // [64 k][64 n + 8 pad] f16
  __shared__ float sONW[64], sONB[64], sOB[64];
  const int t = threadIdx.x;
  const int i = blockIdx.x >> 2;
  const int j0 = (blockIdx.x & 3) << 7;
  const size_t p0 = (size_t)i * 512 + j0;
  const int p = t >> 1, h = t & 1;

  // LN input loads FIRST: latency hides under W staging + barrier.
  // Bit-identical to staged path: o[(h*32+dl)][p0+p] bf16.
  float v[32];
  {
    const unsigned short* op0 = o + (size_t)(h * 32) * 262144 + p0 + p;
    #pragma unroll
    for (int dl = 0; dl < 32; ++dl)
      v[dl] = bf2f(op0[(size_t)dl * 262144]);
  }

  // stage out_w as f16: ldsW[k*72+n]  (RNE; f16 rel err 2^-11, negligible)
  #pragma unroll
  for (int e = 0; e < 16; ++e) {
    const int idx = e * 256 + t;
    ldsW[(idx >> 6) * 72 + (idx & 63)] = (_Float16)out_w[idx];
  }
  if (t < 64) { sONW[t] = onorm_w[t]; sONB[t] = onorm_b[t]; sOB[t] = out_b[t]; }
  __syncthreads();

  // LN stats (pair reduce)
  float s = 0.f, ss = 0.f;
  #pragma unroll
  for (int dl = 0; dl < 32; ++dl) { s += v[dl]; ss += v[dl] * v[dl]; }
  s += __shfl_xor(s, 1); ss += __shfl_xor(ss, 1);
  const float mu = s * 0.015625f;
  const float rs = rsqrtf(ss * 0.015625f - mu * mu + 1e-5f);
  float xv[32];
  #pragma unroll
  for (int dl = 0; dl < 32; ++dl) {
    const int d = h * 32 + dl;
    xv[dl] = (v[dl] - mu) * rs * sONW[d] + sONB[d];
  }

  // matvec: out[p][n0..n0+31] = sum_k xn[p][k] * W[k][n], packed f16
  const int n0 = h * 32;
  _Float16 xA[32], xB[32];   // own k-half / partner k-half (static indexing)
  #pragma unroll
  for (int dl = 0; dl < 32; ++dl) {
    xA[dl] = (_Float16)xv[dl];
    xB[dl] = (_Float16)__shfl_xor(xv[dl], 1);
  }
  float acc[32];
  #pragma unroll
  for (int n = 0; n < 32; ++n) acc[n] = 0.f;
  const int kO = h * 32, kP = (1 - h) * 32;
  #pragma unroll
  for (int pb = 0; pb < 4; ++pb) {       // pb 0,1: own half; 2,3: partner half
    h2 acc2[16];
    #pragma unroll
    for (int n2 = 0; n2 < 16; ++n2) { acc2[n2][0] = (_Float16)0.f; acc2[n2][1] = (_Float16)0.f; }
    #pragma unroll
    for (int kk = 0; kk < 16; ++kk) {
      const int ko = (pb & 1) * 16 + kk;                 // compile-time
      const _Float16 av = (pb < 2) ? xA[ko] : xB[ko];    // compile-time select
      const int k = ((pb < 2) ? kO : kP) + ko;
      h2 a2; a2[0] = av; a2[1] = av;
      const uint4* wr = (const uint4*)(ldsW + k * 72 + n0);  // 144B rows, 16B-aligned
      const uint4 w0 = wr[0], w1 = wr[1], w2 = wr[2], w3 = wr[3];
      const unsigned wu[16] = {w0.x, w0.y, w0.z, w0.w, w1.x, w1.y, w1.z, w1.w,
                               w2.x, w2.y, w2.z, w2.w, w3.x, w3.y, w3.z, w3.w};
      #pragma unroll
      for (int n2 = 0; n2 < 16; ++n2)
        acc2[n2] = a2 * __builtin_bit_cast(h2, wu[n2]) + acc2[n2];  // v_pk_fma_f16
    }
    #pragma unroll
    for (int n2 = 0; n2 < 16; ++n2) {       // fp32 flush every 16 k
      acc[2 * n2]     += (float)acc2[n2][0];
      acc[2 * n2 + 1] += (float)acc2[n2][1];
    }
  }

  // epilogue: +out_b, *ogate (bf16, contiguous per position), fp32 store
  const size_t pl = p0 + p;
  const unsigned short* gp = ogate + pl * 64 + n0;
  float* op = out + pl * 64 + n0;
  #pragma unroll
  for (int c = 0; c < 4; ++c) {
    const uint4 g4 = *(const uint4*)(gp + c * 8);
    const unsigned gg[4] = {g4.x, g4.y, g4.z, g4.w};
    float r[8];
    #pragma unroll
    for (int e = 0; e < 4; ++e) {
      r[2*e]   = (acc[c*8 + 2*e]   + sOB[n0 + c*8 + 2*e])   *
                 bf2f((unsigned short)(gg[e] & 0xffffu));
      r[2*e+1] = (acc[c*8 + 2*e+1] + sOB[n0 + c*8 + 2*e+1]) *
                 bf2f((unsigned short)(gg[e] >> 16));
    }
    float4 s0; s0.x = r[0]; s0.y = r[1]; s0.z = r[2]; s0.w = r[3];
    float4 s1; s1.x = r[4]; s1.y = r[5]; s1.z = r[6]; s1.w = r[7];
    *(float4*)(op + c * 8)     = s0;
    *(float4*)(op + c * 8 + 4) = s1;
  }
}

extern "C" void kernel_launch(void* const* d_in, const int* in_sizes, int n_in,
                              void* d_out, int out_size, void* d_ws, size_t ws_size,
                              hipStream_t stream) {
  const float* x       = (const float*)d_in[0];
  const int*   sm      = (const int*)d_in[1];
  const float* norm_w  = (const float*)d_in[2];
  const float* norm_b  = (const float*)d_in[3];
  const float* left_w  = (const float*)d_in[4];
  const float* left_b  = (const float*)d_in[5];
  const float* right_w = (const float*)d_in[6];
  const float* right_b = (const float*)d_in[7];
  const float* lgate_w = (const float*)d_in[8];
  const float* lgate_b = (const float*)d_in[9];
  const float* rgate_w = (const float*)d_in[10];
  const float* rgate_b = (const float*)d_in[11];
  const float* ogate_w = (const float*)d_in[12];
  const float* ogate_b = (const float*)d_in[13];
  const float* onorm_w = (const float*)d_in[14];
  const float* onorm_b = (const float*)d_in[15];
  const float* out_w   = (const float*)d_in[16];
  const float* out_b   = (const float*)d_in[17];

  char* ws = (char*)d_ws;
  unsigned short* left_t  = (unsigned short*)(ws + 0);          // 33.5 MB
  unsigned short* right_t = (unsigned short*)(ws + 33554432);   // 33.5 MB
  unsigned short* ogate   = (unsigned short*)(ws + 67108864);   // 33.5 MB
  unsigned short* obuf    = (unsigned short*)(ws + 100663296);  // 33.5 MB
  unsigned short* wt      = (unsigned short*)(ws + 134217728);  // 40 KB

  if (ws_size < (size_t)134217728 + 40960) return;  // scratch too small

  k0_prep<<<dim3(20), dim3(256), 0, stream>>>(left_w, right_w, lgate_w, rgate_w,
                                              ogate_w, wt);
  k1_proj<<<dim3(2048), dim3(512), 0, stream>>>(x, sm, norm_w, norm_b, left_b,
                                                right_b, lgate_b, rgate_b,
                                                ogate_b, wt, left_t, right_t,
                                                ogate);
  k2_einsum<<<dim3(256), dim3(512), 0, stream>>>(left_t, right_t, obuf);
  k3_final<<<dim3(2048), dim3(256), 0, stream>>>(obuf, ogate, onorm_w, onorm_b,
                                                 out_w, out_b, (float*)d_out);
}